// Round 4
// baseline (2057.011 us; speedup 1.0000x reference)
//
#include <hip/hip_runtime.h>

#define HID   24
#define T_LEN 4096
#define BATCH 1024
#define NB    2                  // batches per wave (one per 32-lane half)
#define K     8                  // timesteps per chunk (pipeline skew per layer)
#define NC    (T_LEN / K)        // 512 active chunks per layer
#define CTOT  (NC + 2)           // 514 ticks total (3-layer skew)
#define XC    512                // x staging chunk (elements)
#define TPB   192                // 3 full waves: wave w == layer w

__device__ __forceinline__ float dot4(const float4 a, const float4 b, float acc) {
    acc = fmaf(a.x, b.x, acc);
    acc = fmaf(a.y, b.y, acc);
    acc = fmaf(a.z, b.z, acc);
    acc = fmaf(a.w, b.w, acc);
    return acc;
}

__global__ __launch_bounds__(TPB, 2) void rnn_scan_kernel(
    const float* __restrict__ x,     // [B, T]
    const float* __restrict__ h_in,  // [3, B, 24]
    const float* __restrict__ Wih0, const float* __restrict__ bih0,
    const float* __restrict__ Whh0, const float* __restrict__ bhh0,
    const float* __restrict__ Wih1, const float* __restrict__ bih1,
    const float* __restrict__ Whh1, const float* __restrict__ bhh1,
    const float* __restrict__ Wih2, const float* __restrict__ bih2,
    const float* __restrict__ Whh2, const float* __restrict__ bhh2,
    const float* __restrict__ W1,   const float* __restrict__ b1,
    const float* __restrict__ W2,   const float* __restrict__ b2,
    float* __restrict__ out)         // [1024 (y)] ++ [3*1024*24 (h_final)]
{
    // publish buffers: only layers 0 and 1 publish (for layers 1 and 2 resp.)
    __shared__ __align__(16) float hbuf[2][NB][2][K][HID];
    __shared__ __align__(16) float xs[NB][XC];
    __shared__ __align__(16) float h2f[NB][HID];
    __shared__ float mbuf[NB][HID];

    const int tid  = threadIdx.x;
    const int l    = tid >> 6;        // wave id == layer
    const int lane = tid & 63;
    const int bl   = lane >> 5;       // batch half
    const int jj   = lane & 31;
    const bool act = (jj < HID);
    const int j    = act ? jj : 0;    // clamped for safe addressing
    const int bg   = blockIdx.x * NB + bl;
    const int abase = bl << 7;        // bperm byte base: lane (bl*32 + k) -> (bl*128 + 4k)

    // ---- weights in named float4 registers ----
    float4 wi0, wi1, wi2, wi3, wi4, wi5;   // input-from-below row (layers 1,2)
    float4 wh0, wh1, wh2, wh3, wh4, wh5;   // own-h row
    float wx0 = 0.f, bias;
    {
        const float* hhrow = ((l == 0) ? Whh0 : (l == 1) ? Whh1 : Whh2) + j * HID;
        const float4* hh4 = (const float4*)hhrow;
        wh0 = hh4[0]; wh1 = hh4[1]; wh2 = hh4[2];
        wh3 = hh4[3]; wh4 = hh4[4]; wh5 = hh4[5];
        if (l == 0) {
            wx0 = Wih0[j];
            bias = bih0[j] + bhh0[j];
            wi0 = wi1 = wi2 = wi3 = wi4 = wi5 = make_float4(0.f, 0.f, 0.f, 0.f);
        } else {
            const float4* ih4 = (const float4*)(((l == 1) ? Wih1 : Wih2) + j * HID);
            wi0 = ih4[0]; wi1 = ih4[1]; wi2 = ih4[2];
            wi3 = ih4[3]; wi4 = ih4[4]; wi5 = ih4[5];
            bias = (l == 1) ? (bih1[j] + bhh1[j]) : (bih2[j] + bhh2[j]);
        }
    }

    float cur = act ? h_in[(l * BATCH + bg) * HID + j] : 0.f;

    // ---- stage first x region ----
    for (int idx = tid; idx < NB * XC / 4; idx += TPB) {
        const int bb = idx / (XC / 4), o = idx % (XC / 4);
        ((float4*)&xs[bb][0])[o] =
            ((const float4*)(x + (size_t)(blockIdx.x * NB + bb) * T_LEN))[o];
    }
    __syncthreads();

// own-h broadcast via ds_bpermute (register -> register, no LDS RAW chain)
#define BP(K_) __int_as_float(__builtin_amdgcn_ds_bpermute(abase + 4 * (K_), curi))
#define OWN24(A0, A1, A2, A3)                                                      \
    {                                                                              \
        const int curi = __float_as_int(cur);                                      \
        const float h0_ = BP(0), h1_ = BP(1), h2_ = BP(2), h3_ = BP(3);            \
        const float h4_ = BP(4), h5_ = BP(5), h6_ = BP(6), h7_ = BP(7);            \
        const float h8_ = BP(8), h9_ = BP(9), h10_ = BP(10), h11_ = BP(11);        \
        const float h12_ = BP(12), h13_ = BP(13), h14_ = BP(14), h15_ = BP(15);    \
        const float h16_ = BP(16), h17_ = BP(17), h18_ = BP(18), h19_ = BP(19);    \
        const float h20_ = BP(20), h21_ = BP(21), h22_ = BP(22), h23_ = BP(23);    \
        A0 = fmaf(h0_, wh0.x, A0);  A1 = fmaf(h1_, wh0.y, A1);                     \
        A2 = fmaf(h2_, wh0.z, A2);  A3 = fmaf(h3_, wh0.w, A3);                     \
        A0 = fmaf(h4_, wh1.x, A0);  A1 = fmaf(h5_, wh1.y, A1);                     \
        A2 = fmaf(h6_, wh1.z, A2);  A3 = fmaf(h7_, wh1.w, A3);                     \
        A0 = fmaf(h8_, wh2.x, A0);  A1 = fmaf(h9_, wh2.y, A1);                     \
        A2 = fmaf(h10_, wh2.z, A2); A3 = fmaf(h11_, wh2.w, A3);                    \
        A0 = fmaf(h12_, wh3.x, A0); A1 = fmaf(h13_, wh3.y, A1);                    \
        A2 = fmaf(h14_, wh3.z, A2); A3 = fmaf(h15_, wh3.w, A3);                    \
        A0 = fmaf(h16_, wh4.x, A0); A1 = fmaf(h17_, wh4.y, A1);                    \
        A2 = fmaf(h18_, wh4.z, A2); A3 = fmaf(h19_, wh4.w, A3);                    \
        A0 = fmaf(h20_, wh5.x, A0); A1 = fmaf(h21_, wh5.y, A1);                    \
        A2 = fmaf(h22_, wh5.z, A2); A3 = fmaf(h23_, wh5.w, A3);                    \
    }

    // ---- chunked, layer-skewed scan ----
    for (int c = 0; c < CTOT; ++c) {
        const int wp = c & 1, rp = wp ^ 1;
        if (c >= l && c < l + NC) {
            if (l == 0) {
                const int xoff = (c * K) & (XC - 1);
                // prefetch the chunk's 8 x values (broadcast reads, off-chain)
                const float4 xq0 = *(const float4*)&xs[bl][xoff];
                const float4 xq1 = *(const float4*)&xs[bl][xoff + 4];
                #pragma unroll
                for (int s = 0; s < K; ++s) {
                    const float xv = (s == 0) ? xq0.x : (s == 1) ? xq0.y
                                   : (s == 2) ? xq0.z : (s == 3) ? xq0.w
                                   : (s == 4) ? xq1.x : (s == 5) ? xq1.y
                                   : (s == 6) ? xq1.z : xq1.w;
                    float a0 = wx0 * xv, a1 = 0.f, a2 = 0.f, a3 = 0.f;
                    OWN24(a0, a1, a2, a3);
                    cur = fmaxf(bias + ((a0 + a1) + (a2 + a3)), 0.f);
                    if (act) hbuf[wp][bl][0][s][j] = cur;
                }
            } else {
                // prefetch step-0 input vector into registers
                float4 p0, p1, p2, p3, p4, p5;
                {
                    const float4* r = (const float4*)&hbuf[rp][bl][l - 1][0][0];
                    p0 = r[0]; p1 = r[1]; p2 = r[2]; p3 = r[3]; p4 = r[4]; p5 = r[5];
                }
                #pragma unroll
                for (int s = 0; s < K; ++s) {
                    float4 n0, n1, n2, n3, n4, n5;
                    if (s + 1 < K) {
                        const float4* r = (const float4*)&hbuf[rp][bl][l - 1][s + 1][0];
                        n0 = r[0]; n1 = r[1]; n2 = r[2]; n3 = r[3]; n4 = r[4]; n5 = r[5];
                    }
                    float a0 = 0.f, a1 = 0.f, a2 = 0.f, a3 = 0.f;
                    OWN24(a0, a1, a2, a3);
                    a0 = dot4(wi0, p0, a0); a1 = dot4(wi1, p1, a1);
                    a2 = dot4(wi2, p2, a2); a3 = dot4(wi3, p3, a3);
                    a0 = dot4(wi4, p4, a0); a1 = dot4(wi5, p5, a1);
                    cur = fmaxf(bias + ((a0 + a1) + (a2 + a3)), 0.f);
                    if (act && l == 1) hbuf[wp][bl][1][s][j] = cur;
                    if (s + 1 < K) { p0 = n0; p1 = n1; p2 = n2; p3 = n3; p4 = n4; p5 = n5; }
                }
            }
        }
        __syncthreads();
        // stage next x region when the next chunk crosses an XC boundary
        const int cn = c + 1;
        if (cn < NC && ((cn * K) & (XC - 1)) == 0) {
            for (int idx = tid; idx < NB * XC / 4; idx += TPB) {
                const int bb = idx / (XC / 4), o = idx % (XC / 4);
                ((float4*)&xs[bb][0])[o] =
                    ((const float4*)(x + (size_t)(blockIdx.x * NB + bb) * T_LEN + cn * K))[o];
            }
            __syncthreads();
        }
    }
#undef OWN24
#undef BP

    // ---- h_final from registers ----
    if (act) out[BATCH + (l * BATCH + bg) * HID + j] = cur;

    // ---- MLP head on h2(T-1) ----
    if (l == 2 && act) h2f[bl][j] = cur;
    __syncthreads();
    if (l == 2 && act) {
        const float4* w1r = (const float4*)(W1 + j * HID);
        const float4* hv  = (const float4*)&h2f[bl][0];
        float a = b1[j];
        a = dot4(w1r[0], hv[0], a); a = dot4(w1r[1], hv[1], a);
        a = dot4(w1r[2], hv[2], a); a = dot4(w1r[3], hv[3], a);
        a = dot4(w1r[4], hv[4], a); a = dot4(w1r[5], hv[5], a);
        mbuf[bl][j] = fmaxf(a, 0.f);
    }
    __syncthreads();
    if (l == 2 && jj == 0) {
        float a = b2[0];
        #pragma unroll
        for (int k = 0; k < HID; ++k) a = fmaf(W2[k], mbuf[bl][k], a);
        out[bg] = fmaxf(a, 0.f);
    }
}

extern "C" void kernel_launch(void* const* d_in, const int* in_sizes, int n_in,
                              void* d_out, int out_size, void* d_ws, size_t ws_size,
                              hipStream_t stream) {
    const float* x    = (const float*)d_in[0];
    const float* h_in = (const float*)d_in[1];
    const float* Wih0 = (const float*)d_in[2];
    const float* bih0 = (const float*)d_in[3];
    const float* Whh0 = (const float*)d_in[4];
    const float* bhh0 = (const float*)d_in[5];
    const float* Wih1 = (const float*)d_in[6];
    const float* bih1 = (const float*)d_in[7];
    const float* Whh1 = (const float*)d_in[8];
    const float* bhh1 = (const float*)d_in[9];
    const float* Wih2 = (const float*)d_in[10];
    const float* bih2 = (const float*)d_in[11];
    const float* Whh2 = (const float*)d_in[12];
    const float* bhh2 = (const float*)d_in[13];
    const float* W1   = (const float*)d_in[14];
    const float* b1   = (const float*)d_in[15];
    const float* W2   = (const float*)d_in[16];
    const float* b2   = (const float*)d_in[17];
    float* out = (float*)d_out;

    dim3 grid(BATCH / NB);   // 512 blocks -> 2 blocks/CU
    dim3 block(TPB);         // 3 full waves (wave == layer)
    hipLaunchKernelGGL(rnn_scan_kernel, grid, block, 0, stream,
                       x, h_in, Wih0, bih0, Whh0, bhh0,
                       Wih1, bih1, Whh1, bhh1, Wih2, bih2, Whh2, bhh2,
                       W1, b1, W2, b2, out);
}